// Round 2
// baseline (977.403 us; speedup 1.0000x reference)
//
#include <hip/hip_runtime.h>
#include <math.h>

// SPDNet collapse: both ReEig clamps are inactive (lambda_min >= 1e-3 > 1e-4 by
// construction), so:  out = vec(logm(V^T x V)) @ w_lin^T + b_lin,  V = w1@w2.
// One thread per matrix; 11x11 Jacobi fully unrolled in registers.
//
// R9 (R8 post-mortem: waves_per_eu(2) = min2/max8 -> allocator chased 8 waves,
// halved to 128 VGPR, spilled all Jacobi state: FETCH 48MB->1.2GB, 3.4x slower):
//  - waves_per_eu(2,2): min=max=2 caps VGPR at 256 (which R7's build already
//    fit exactly, zero spills) and forbids the occupancy-chasing 128-reg build.
//    256 VGPR natively supports 2 waves/SIMD (pool=512/lane/SIMD); R7's (1,1)
//    was the only thing pinning it to 1 wave.
//  - keep R8 formation: M = V^T (X V) in 4-row blocks (no T[132]; peak live
//    ~160 formation / ~205 Jacobi) -> slack under the 256 cap.
//  - keep: NSWEEP 5, round-phase split (5 disjoint (c,s) chains before applies),
//    copysign rotation chain, prep kernel + wave-uniform epilogue.

#define NSWEEP 5

// d_ws float layout: [0..143] V (12x12, col 11 zero) | [160..211] b_lin |
//                    [256..256+52*68) Ws_sym rows padded to 68
#define WS_V 0
#define WS_B 160
#define WS_W 256

__device__ __forceinline__ constexpr int UT(int i, int j) { // i<=j, n=11 upper tri
  return i * 11 - (i * (i - 1)) / 2 + (j - i);
}

template <int P, int Q>
__device__ __forceinline__ void csCompute(const float (&M)[66], float& c, float& s,
                                          float& t) {
  const float app = M[UT(P, P)], aqq = M[UT(Q, Q)], apq = M[UT(P, Q)];
  const float d2 = aqq - app;
  const float a2 = apq + apq;
  const float r = __builtin_amdgcn_sqrtf(
      __builtin_fmaf(d2, d2, __builtin_fmaf(a2, a2, 1e-60f)));
  const float den = d2 + __builtin_copysignf(r, d2);
  t = a2 * __builtin_amdgcn_rcpf(den);
  c = __builtin_amdgcn_rsqf(__builtin_fmaf(t, t, 1.0f));
  s = t * c;
}

template <int P, int Q>
__device__ __forceinline__ void applyRot(float (&M)[66], float (&U)[121], float c,
                                         float s, float t) {
  const float apq = M[UT(P, Q)];
#pragma unroll
  for (int k = 0; k < 11; ++k) {
    if (k == P || k == Q) continue;
    const int ikp = (k < P) ? UT(k, P) : UT(P, k);
    const int ikq = (k < Q) ? UT(k, Q) : UT(Q, k);
    const float akp = M[ikp], akq = M[ikq];
    M[ikp] = __builtin_fmaf(c, akp, -s * akq);
    M[ikq] = __builtin_fmaf(s, akp, c * akq);
  }
  M[UT(P, P)] = __builtin_fmaf(-t, apq, M[UT(P, P)]);
  M[UT(Q, Q)] = __builtin_fmaf(t, apq, M[UT(Q, Q)]);
  M[UT(P, Q)] = 0.0f;
#pragma unroll
  for (int k = 0; k < 11; ++k) {
    const float ukp = U[k * 11 + P], ukq = U[k * 11 + Q];
    U[k * 11 + P] = __builtin_fmaf(c, ukp, -s * ukq);
    U[k * 11 + Q] = __builtin_fmaf(s, ukp, c * ukq);
  }
}

// Round-robin pairs: round R, K=1..5 -> 5 disjoint pairs; 11 rounds = all 55.
template <int R, int K>
struct PairRR {
  static constexpr int A0 = (R + K) % 11;
  static constexpr int B0 = (R + 11 - K) % 11;
  static constexpr int P = A0 < B0 ? A0 : B0;
  static constexpr int Q = A0 < B0 ? B0 : A0;
};

template <int R>
__device__ __forceinline__ void jround(float (&M)[66], float (&U)[121]) {
  float c1, s1, t1, c2, s2, t2, c3, s3, t3, c4, s4, t4, c5, s5, t5;
  csCompute<PairRR<R, 1>::P, PairRR<R, 1>::Q>(M, c1, s1, t1);
  csCompute<PairRR<R, 2>::P, PairRR<R, 2>::Q>(M, c2, s2, t2);
  csCompute<PairRR<R, 3>::P, PairRR<R, 3>::Q>(M, c3, s3, t3);
  csCompute<PairRR<R, 4>::P, PairRR<R, 4>::Q>(M, c4, s4, t4);
  csCompute<PairRR<R, 5>::P, PairRR<R, 5>::Q>(M, c5, s5, t5);
  applyRot<PairRR<R, 1>::P, PairRR<R, 1>::Q>(M, U, c1, s1, t1);
  applyRot<PairRR<R, 2>::P, PairRR<R, 2>::Q>(M, U, c2, s2, t2);
  applyRot<PairRR<R, 3>::P, PairRR<R, 3>::Q>(M, U, c3, s3, t3);
  applyRot<PairRR<R, 4>::P, PairRR<R, 4>::Q>(M, U, c4, s4, t4);
  applyRot<PairRR<R, 5>::P, PairRR<R, 5>::Q>(M, U, c5, s5, t5);
}

template <int R>
struct RoundSeq {
  static __device__ __forceinline__ void run(float (&M)[66], float (&U)[121]) {
    jround<R>(M, U);
    if constexpr (R < 10) RoundSeq<R + 1>::run(M, U);
  }
};

__global__ __launch_bounds__(256) void prep_kernel(
    const float* __restrict__ w1, const float* __restrict__ w2,
    const float* __restrict__ wlin, const float* __restrict__ blin,
    float* __restrict__ ws) {
  const int g = blockIdx.x * 256 + threadIdx.x;
  const int gs = gridDim.x * 256;
  for (int idx = g; idx < 144; idx += gs) {
    const int i = idx / 12, l = idx % 12;
    float acc = 0.f;
    if (l < 11) {
#pragma unroll
      for (int j = 0; j < 12; ++j) acc = __builtin_fmaf(w1[i * 12 + j], w2[j * 11 + l], acc);
    }
    ws[WS_V + idx] = acc;
  }
  for (int idx = g; idx < 52; idx += gs) ws[WS_B + idx] = blin[idx];
  for (int idx = g; idx < 52 * 68; idx += gs) {
    const int c = idx / 68, t = idx % 68;
    float v = 0.f;
    if (t < 66) {
      int i = 0, rem = t;
      while (rem >= 11 - i) { rem -= 11 - i; ++i; }
      const int j = i + rem;
      v = wlin[c * 121 + i * 11 + j];
      if (i != j) v += wlin[c * 121 + j * 11 + i];
    }
    ws[WS_W + idx] = v;
  }
}

__global__ __attribute__((amdgpu_flat_work_group_size(256, 256)))
__attribute__((amdgpu_waves_per_eu(2, 2)))
void manifold_kernel(const float* __restrict__ x, const float* __restrict__ ws,
                     float* __restrict__ out, int B) {
  __shared__ __align__(16) float sV[12 * 12];
  const int tid = threadIdx.x;
  if (tid < 36) {
    reinterpret_cast<float4*>(sV)[tid] =
        reinterpret_cast<const float4*>(ws + WS_V)[tid];
  }
  __syncthreads();

  const int b = blockIdx.x * 256 + tid;
  if (b >= B) return;

  // ---- Formation: M = V^T (X V), 4 X-rows per block. Per block:
  //   w[r][l] = sum_j X[i][j] V[j][l]  (V rows broadcast from LDS)
  //   M[k][l] += V[i][k] w[r][l]       (upper triangle only)
  // Peak live: xr[48] + w[44] + M[66] ~ 160 regs (no T[132]).
  float M[66];
#pragma unroll
  for (int e = 0; e < 66; ++e) M[e] = 0.f;
  const float4* xb4 = reinterpret_cast<const float4*>(x + (size_t)b * 144);
#pragma unroll 1
  for (int ib = 0; ib < 3; ++ib) {
    float xr[4][12];
#pragma unroll
    for (int r = 0; r < 4; ++r) {
      const float4 a0 = xb4[(ib * 4 + r) * 3 + 0];
      const float4 a1 = xb4[(ib * 4 + r) * 3 + 1];
      const float4 a2 = xb4[(ib * 4 + r) * 3 + 2];
      xr[r][0] = a0.x; xr[r][1] = a0.y; xr[r][2] = a0.z; xr[r][3] = a0.w;
      xr[r][4] = a1.x; xr[r][5] = a1.y; xr[r][6] = a1.z; xr[r][7] = a1.w;
      xr[r][8] = a2.x; xr[r][9] = a2.y; xr[r][10] = a2.z; xr[r][11] = a2.w;
    }
    float w[4][11];
#pragma unroll
    for (int r = 0; r < 4; ++r)
#pragma unroll
      for (int l = 0; l < 11; ++l) w[r][l] = 0.f;
#pragma unroll
    for (int j = 0; j < 12; ++j) {
      const float4 v0 = *reinterpret_cast<const float4*>(&sV[j * 12 + 0]);
      const float4 v1 = *reinterpret_cast<const float4*>(&sV[j * 12 + 4]);
      const float4 v2 = *reinterpret_cast<const float4*>(&sV[j * 12 + 8]);
      const float vr[11] = {v0.x, v0.y, v0.z, v0.w, v1.x, v1.y, v1.z, v1.w,
                            v2.x, v2.y, v2.z};
#pragma unroll
      for (int r = 0; r < 4; ++r)
#pragma unroll
        for (int l = 0; l < 11; ++l)
          w[r][l] = __builtin_fmaf(xr[r][j], vr[l], w[r][l]);
    }
#pragma unroll
    for (int r = 0; r < 4; ++r) {
      const int i = ib * 4 + r;
      const float4 u0 = *reinterpret_cast<const float4*>(&sV[i * 12 + 0]);
      const float4 u1 = *reinterpret_cast<const float4*>(&sV[i * 12 + 4]);
      const float4 u2 = *reinterpret_cast<const float4*>(&sV[i * 12 + 8]);
      const float ui[11] = {u0.x, u0.y, u0.z, u0.w, u1.x, u1.y, u1.z, u1.w,
                            u2.x, u2.y, u2.z};
#pragma unroll
      for (int k = 0; k < 11; ++k)
#pragma unroll
        for (int l = k; l < 11; ++l)
          M[UT(k, l)] = __builtin_fmaf(ui[k], w[r][l], M[UT(k, l)]);
    }
  }

  // ---- Jacobi eigendecomposition ----
  float U[121];
#pragma unroll
  for (int e = 0; e < 121; ++e) U[e] = 0.f;
#pragma unroll
  for (int d = 0; d < 11; ++d) U[d * 11 + d] = 1.f;
#pragma unroll 1
  for (int sweep = 0; sweep < NSWEEP; ++sweep) {
    RoundSeq<0>::run(M, U);
  }

  // ---- eigen-log (clamp matches the reference's preceding ReEig) ----
  float lw[11];
#pragma unroll
  for (int k = 0; k < 11; ++k) lw[k] = __logf(fmaxf(M[UT(k, k)], 1e-4f));

  // ---- L = U diag(lw) U^T row-by-row; U row i retires after L row i ----
  float L[66];
#pragma unroll
  for (int i = 0; i < 11; ++i) {
    float tk[11];
#pragma unroll
    for (int k = 0; k < 11; ++k) tk[k] = lw[k] * U[i * 11 + k];
#pragma unroll
    for (int j = i; j < 11; ++j) {
      float acc = 0.f;
#pragma unroll
      for (int k = 0; k < 11; ++k) acc = __builtin_fmaf(tk[k], U[j * 11 + k], acc);
      L[UT(i, j)] = acc;
    }
  }

  // ---- epilogue: Ws/b_lin via wave-uniform global loads (scalar cache) ----
  const float* __restrict__ wsym = ws + WS_W;
  const float* __restrict__ bl = ws + WS_B;
  float* ob = out + (size_t)b * 52;
#pragma unroll 1
  for (int c4 = 0; c4 < 13; ++c4) {
    float ov[4];
#pragma unroll
    for (int cc = 0; cc < 4; ++cc) {
      const int c = c4 * 4 + cc;
      const float* wr = wsym + c * 68;
      float a0 = 0.f, a1 = 0.f, a2 = 0.f, a3 = 0.f;
#pragma unroll
      for (int t = 0; t < 64; t += 4) {
        a0 = __builtin_fmaf(wr[t + 0], L[t + 0], a0);
        a1 = __builtin_fmaf(wr[t + 1], L[t + 1], a1);
        a2 = __builtin_fmaf(wr[t + 2], L[t + 2], a2);
        a3 = __builtin_fmaf(wr[t + 3], L[t + 3], a3);
      }
      a0 = __builtin_fmaf(wr[64], L[64], a0);
      a1 = __builtin_fmaf(wr[65], L[65], a1);
      ov[cc] = bl[c] + ((a0 + a1) + (a2 + a3));
    }
    float4 o;
    o.x = ov[0]; o.y = ov[1]; o.z = ov[2]; o.w = ov[3];
    reinterpret_cast<float4*>(ob)[c4] = o;
  }
}

extern "C" void kernel_launch(void* const* d_in, const int* in_sizes, int n_in,
                              void* d_out, int out_size, void* d_ws, size_t ws_size,
                              hipStream_t stream) {
  const float* x = (const float*)d_in[0];
  const float* w1 = (const float*)d_in[1];
  const float* w2 = (const float*)d_in[2];
  const float* wlin = (const float*)d_in[3];
  const float* blin = (const float*)d_in[4];
  float* out = (float*)d_out;
  float* ws = (float*)d_ws;  // needs 3792 floats (~15 KB)
  const int B = in_sizes[0] / 144;  // 131072
  hipLaunchKernelGGL(prep_kernel, dim3(8), dim3(256), 0, stream,
                     w1, w2, wlin, blin, ws);
  const int grid = (B + 255) / 256;
  hipLaunchKernelGGL(manifold_kernel, dim3(grid), dim3(256), 0, stream,
                     x, ws, out, B);
}

// Round 3
// 266.564 us; speedup vs baseline: 3.6667x; 3.6667x over previous
//
#include <hip/hip_runtime.h>
#include <math.h>

// SPDNet collapse: both ReEig clamps are inactive (lambda_min >= 1e-3 > 1e-4 by
// construction), so:  out = vec(logm(V^T x V)) @ w_lin^T + b_lin,  V = w1@w2.
// One thread per matrix; 11x11 Jacobi fully unrolled in registers.
//
// R10 (R8/R9 post-mortem: compiler maps min-2-waves/EU -> 128 VGPR cap and HW
// gives 2 waves/SIMD only at <=128 regs; Jacobi state M66+U121=187 can't fit.
// Occupancy door closed -> attack VALU-issue count with packed FP32 instead):
//  - back to waves_per_eu(1,1), the proven 256-VGPR no-spill operating point.
//  - U stored column-major as v2f U2[66] (11 cols x 6 row-pairs, padded row 11);
//    rotation updates become v_pk_mul/v_pk_fma: 24 ops vs 44 scalar per rotation.
//  - epilogue packed: L as v2f L2[33], wave-uniform weights read as v2f
//    (pk_fma takes one SGPR-pair source): 33 pk_fma vs 66 per class.
//  - formation w-accumulation packed along l (V col 11 is zero -> pad lane is
//    self-annihilating). M stays scalar upper-tri (packed full-sym M costs
//    68 ops/rot vs 40 scalar-tri -- checked, loses).
//  - per-slot math bit-identical (same fma trees); only epilogue accumulator
//    grouping reassociates (~1e-6).
//  - keep: NSWEEP 5, round-phase split, copysign rotation chain, prep kernel.

#define NSWEEP 5

// d_ws float layout: [0..143] V (12x12, col 11 zero) | [160..211] b_lin |
//                    [256..256+52*68) Ws_sym rows padded to 68
#define WS_V 0
#define WS_B 160
#define WS_W 256

typedef float v2f __attribute__((ext_vector_type(2)));

__device__ __forceinline__ v2f fma2(v2f a, v2f b, v2f c) {
  return __builtin_elementwise_fma(a, b, c);
}
__device__ __forceinline__ v2f sp2(float x) {
  v2f r; r.x = x; r.y = x; return r;
}

__device__ __forceinline__ constexpr int UT(int i, int j) { // i<=j, n=11 upper tri
  return i * 11 - (i * (i - 1)) / 2 + (j - i);
}

template <int P, int Q>
__device__ __forceinline__ void csCompute(const float (&M)[66], float& c, float& s,
                                          float& t) {
  const float app = M[UT(P, P)], aqq = M[UT(Q, Q)], apq = M[UT(P, Q)];
  const float d2 = aqq - app;
  const float a2 = apq + apq;
  const float r = __builtin_amdgcn_sqrtf(
      __builtin_fmaf(d2, d2, __builtin_fmaf(a2, a2, 1e-60f)));
  const float den = d2 + __builtin_copysignf(r, d2);
  t = a2 * __builtin_amdgcn_rcpf(den);
  c = __builtin_amdgcn_rsqf(__builtin_fmaf(t, t, 1.0f));
  s = t * c;
}

// M: scalar upper-tri (66). U2: column-major packed, col j = U2[j*6 .. j*6+5],
// rows (2*r2, 2*r2+1); row 11 is padding (stays 0, never read back).
template <int P, int Q>
__device__ __forceinline__ void applyRot(float (&M)[66], v2f (&U2)[66], float c,
                                         float s, float t) {
  const float apq = M[UT(P, Q)];
#pragma unroll
  for (int k = 0; k < 11; ++k) {
    if (k == P || k == Q) continue;
    const int ikp = (k < P) ? UT(k, P) : UT(P, k);
    const int ikq = (k < Q) ? UT(k, Q) : UT(Q, k);
    const float akp = M[ikp], akq = M[ikq];
    M[ikp] = __builtin_fmaf(c, akp, -s * akq);
    M[ikq] = __builtin_fmaf(s, akp, c * akq);
  }
  M[UT(P, P)] = __builtin_fmaf(-t, apq, M[UT(P, P)]);
  M[UT(Q, Q)] = __builtin_fmaf(t, apq, M[UT(Q, Q)]);
  M[UT(P, Q)] = 0.0f;
  const v2f c2 = sp2(c), s2 = sp2(s);
#pragma unroll
  for (int r2 = 0; r2 < 6; ++r2) {
    const v2f up = U2[P * 6 + r2], uq = U2[Q * 6 + r2];
    U2[P * 6 + r2] = fma2(c2, up, -(s2 * uq));   // c*up - s*uq  (2 rows/op)
    U2[Q * 6 + r2] = fma2(s2, up, c2 * uq);      // s*up + c*uq
  }
}

// Round-robin pairs: round R, K=1..5 -> 5 disjoint pairs; 11 rounds = all 55.
template <int R, int K>
struct PairRR {
  static constexpr int A0 = (R + K) % 11;
  static constexpr int B0 = (R + 11 - K) % 11;
  static constexpr int P = A0 < B0 ? A0 : B0;
  static constexpr int Q = A0 < B0 ? B0 : A0;
};

template <int R>
__device__ __forceinline__ void jround(float (&M)[66], v2f (&U2)[66]) {
  float c1, s1, t1, c2, s2, t2, c3, s3, t3, c4, s4, t4, c5, s5, t5;
  csCompute<PairRR<R, 1>::P, PairRR<R, 1>::Q>(M, c1, s1, t1);
  csCompute<PairRR<R, 2>::P, PairRR<R, 2>::Q>(M, c2, s2, t2);
  csCompute<PairRR<R, 3>::P, PairRR<R, 3>::Q>(M, c3, s3, t3);
  csCompute<PairRR<R, 4>::P, PairRR<R, 4>::Q>(M, c4, s4, t4);
  csCompute<PairRR<R, 5>::P, PairRR<R, 5>::Q>(M, c5, s5, t5);
  applyRot<PairRR<R, 1>::P, PairRR<R, 1>::Q>(M, U2, c1, s1, t1);
  applyRot<PairRR<R, 2>::P, PairRR<R, 2>::Q>(M, U2, c2, s2, t2);
  applyRot<PairRR<R, 3>::P, PairRR<R, 3>::Q>(M, U2, c3, s3, t3);
  applyRot<PairRR<R, 4>::P, PairRR<R, 4>::Q>(M, U2, c4, s4, t4);
  applyRot<PairRR<R, 5>::P, PairRR<R, 5>::Q>(M, U2, c5, s5, t5);
}

template <int R>
struct RoundSeq {
  static __device__ __forceinline__ void run(float (&M)[66], v2f (&U2)[66]) {
    jround<R>(M, U2);
    if constexpr (R < 10) RoundSeq<R + 1>::run(M, U2);
  }
};

__global__ __launch_bounds__(256) void prep_kernel(
    const float* __restrict__ w1, const float* __restrict__ w2,
    const float* __restrict__ wlin, const float* __restrict__ blin,
    float* __restrict__ ws) {
  const int g = blockIdx.x * 256 + threadIdx.x;
  const int gs = gridDim.x * 256;
  for (int idx = g; idx < 144; idx += gs) {
    const int i = idx / 12, l = idx % 12;
    float acc = 0.f;
    if (l < 11) {
#pragma unroll
      for (int j = 0; j < 12; ++j) acc = __builtin_fmaf(w1[i * 12 + j], w2[j * 11 + l], acc);
    }
    ws[WS_V + idx] = acc;
  }
  for (int idx = g; idx < 52; idx += gs) ws[WS_B + idx] = blin[idx];
  for (int idx = g; idx < 52 * 68; idx += gs) {
    const int c = idx / 68, t = idx % 68;
    float v = 0.f;
    if (t < 66) {
      int i = 0, rem = t;
      while (rem >= 11 - i) { rem -= 11 - i; ++i; }
      const int j = i + rem;
      v = wlin[c * 121 + i * 11 + j];
      if (i != j) v += wlin[c * 121 + j * 11 + i];
    }
    ws[WS_W + idx] = v;
  }
}

__global__ __attribute__((amdgpu_flat_work_group_size(256, 256)))
__attribute__((amdgpu_waves_per_eu(1, 1)))
void manifold_kernel(const float* __restrict__ x, const float* __restrict__ ws,
                     float* __restrict__ out, int B) {
  __shared__ __align__(16) float sV[12 * 12];
  const int tid = threadIdx.x;
  if (tid < 36) {
    reinterpret_cast<float4*>(sV)[tid] =
        reinterpret_cast<const float4*>(ws + WS_V)[tid];
  }
  __syncthreads();

  const int b = blockIdx.x * 256 + tid;
  if (b >= B) return;

  // ---- Formation: M = V^T (X V), 4 X-rows per block. w packed along l
  // (v2f w2[4][6]; pad lane l=11 multiplies V col 11 == 0, stays 0).
  float M[66];
#pragma unroll
  for (int e = 0; e < 66; ++e) M[e] = 0.f;
  const float4* xb4 = reinterpret_cast<const float4*>(x + (size_t)b * 144);
#pragma unroll 1
  for (int ib = 0; ib < 3; ++ib) {
    float xr[4][12];
#pragma unroll
    for (int r = 0; r < 4; ++r) {
      const float4 a0 = xb4[(ib * 4 + r) * 3 + 0];
      const float4 a1 = xb4[(ib * 4 + r) * 3 + 1];
      const float4 a2 = xb4[(ib * 4 + r) * 3 + 2];
      xr[r][0] = a0.x; xr[r][1] = a0.y; xr[r][2] = a0.z; xr[r][3] = a0.w;
      xr[r][4] = a1.x; xr[r][5] = a1.y; xr[r][6] = a1.z; xr[r][7] = a1.w;
      xr[r][8] = a2.x; xr[r][9] = a2.y; xr[r][10] = a2.z; xr[r][11] = a2.w;
    }
    v2f w2[4][6];
#pragma unroll
    for (int r = 0; r < 4; ++r)
#pragma unroll
      for (int l2 = 0; l2 < 6; ++l2) { w2[r][l2].x = 0.f; w2[r][l2].y = 0.f; }
#pragma unroll
    for (int j = 0; j < 12; ++j) {
      v2f vj[6];
      {
        const float4 v0 = *reinterpret_cast<const float4*>(&sV[j * 12 + 0]);
        const float4 v1 = *reinterpret_cast<const float4*>(&sV[j * 12 + 4]);
        const float4 v2 = *reinterpret_cast<const float4*>(&sV[j * 12 + 8]);
        vj[0].x = v0.x; vj[0].y = v0.y; vj[1].x = v0.z; vj[1].y = v0.w;
        vj[2].x = v1.x; vj[2].y = v1.y; vj[3].x = v1.z; vj[3].y = v1.w;
        vj[4].x = v2.x; vj[4].y = v2.y; vj[5].x = v2.z; vj[5].y = v2.w;
      }
#pragma unroll
      for (int r = 0; r < 4; ++r) {
        const v2f xb = sp2(xr[r][j]);
#pragma unroll
        for (int l2 = 0; l2 < 6; ++l2) w2[r][l2] = fma2(xb, vj[l2], w2[r][l2]);
      }
    }
#pragma unroll
    for (int r = 0; r < 4; ++r) {
      const int i = ib * 4 + r;
      const float4 u0 = *reinterpret_cast<const float4*>(&sV[i * 12 + 0]);
      const float4 u1 = *reinterpret_cast<const float4*>(&sV[i * 12 + 4]);
      const float4 u2 = *reinterpret_cast<const float4*>(&sV[i * 12 + 8]);
      const float ui[11] = {u0.x, u0.y, u0.z, u0.w, u1.x, u1.y, u1.z, u1.w,
                            u2.x, u2.y, u2.z};
      float wv[11];  // free register aliases of w2 halves
#pragma unroll
      for (int l = 0; l < 11; ++l)
        wv[l] = (l & 1) ? w2[r][l >> 1].y : w2[r][l >> 1].x;
#pragma unroll
      for (int k = 0; k < 11; ++k)
#pragma unroll
        for (int l = k; l < 11; ++l)
          M[UT(k, l)] = __builtin_fmaf(ui[k], wv[l], M[UT(k, l)]);
    }
  }

  // ---- Jacobi eigendecomposition; U column-major packed in v2f ----
  v2f U2[66];
#pragma unroll
  for (int e = 0; e < 66; ++e) { U2[e].x = 0.f; U2[e].y = 0.f; }
#pragma unroll
  for (int d = 0; d < 11; ++d) {
    if (d & 1) U2[d * 6 + (d >> 1)].y = 1.f;
    else       U2[d * 6 + (d >> 1)].x = 1.f;
  }
#pragma unroll 1
  for (int sweep = 0; sweep < NSWEEP; ++sweep) {
    RoundSeq<0>::run(M, U2);
  }

  // ---- eigen-log (clamp matches the reference's preceding ReEig) ----
  float lw[11];
#pragma unroll
  for (int k = 0; k < 11; ++k) lw[k] = __logf(fmaxf(M[UT(k, k)], 1e-4f));

  // ---- L = U diag(lw) U^T, written directly into packed v2f L2[33].
  // U[i][k] = (row i, col k) = half (i&1) of U2[k*6 + (i>>1)] -- free alias.
  v2f L2[33];
#pragma unroll
  for (int i = 0; i < 11; ++i) {
    float tk[11];
#pragma unroll
    for (int k = 0; k < 11; ++k) {
      const v2f u = U2[k * 6 + (i >> 1)];
      const float uik = (i & 1) ? u.y : u.x;
      tk[k] = lw[k] * uik;
    }
#pragma unroll
    for (int j = i; j < 11; ++j) {
      float acc = 0.f;
#pragma unroll
      for (int k = 0; k < 11; ++k) {
        const v2f u = U2[k * 6 + (j >> 1)];
        const float ujk = (j & 1) ? u.y : u.x;
        acc = __builtin_fmaf(tk[k], ujk, acc);
      }
      const int idx = UT(i, j);
      if (idx & 1) L2[idx >> 1].y = acc;
      else         L2[idx >> 1].x = acc;
    }
  }

  // ---- epilogue: packed pk_fma; weights wave-uniform (SGPR-pair source) ----
  const float* __restrict__ wsym = ws + WS_W;
  const float* __restrict__ bl = ws + WS_B;
  float* ob = out + (size_t)b * 52;
#pragma unroll 1
  for (int c4 = 0; c4 < 13; ++c4) {
    float ov[4];
#pragma unroll
    for (int cc = 0; cc < 4; ++cc) {
      const int c = c4 * 4 + cc;
      const v2f* __restrict__ wr2 = reinterpret_cast<const v2f*>(wsym + c * 68);
      v2f a0 = sp2(0.f), a1 = sp2(0.f), a2 = sp2(0.f);
#pragma unroll
      for (int t = 0; t < 30; t += 3) {
        a0 = fma2(wr2[t + 0], L2[t + 0], a0);
        a1 = fma2(wr2[t + 1], L2[t + 1], a1);
        a2 = fma2(wr2[t + 2], L2[t + 2], a2);
      }
      a0 = fma2(wr2[30], L2[30], a0);
      a1 = fma2(wr2[31], L2[31], a1);
      a2 = fma2(wr2[32], L2[32], a2);
      const v2f sum = (a0 + a1) + a2;
      ov[cc] = bl[c] + (sum.x + sum.y);
    }
    float4 o;
    o.x = ov[0]; o.y = ov[1]; o.z = ov[2]; o.w = ov[3];
    reinterpret_cast<float4*>(ob)[c4] = o;
  }
}

extern "C" void kernel_launch(void* const* d_in, const int* in_sizes, int n_in,
                              void* d_out, int out_size, void* d_ws, size_t ws_size,
                              hipStream_t stream) {
  const float* x = (const float*)d_in[0];
  const float* w1 = (const float*)d_in[1];
  const float* w2 = (const float*)d_in[2];
  const float* wlin = (const float*)d_in[3];
  const float* blin = (const float*)d_in[4];
  float* out = (float*)d_out;
  float* ws = (float*)d_ws;  // needs 3792 floats (~15 KB)
  const int B = in_sizes[0] / 144;  // 131072
  hipLaunchKernelGGL(prep_kernel, dim3(8), dim3(256), 0, stream,
                     w1, w2, wlin, blin, ws);
  const int grid = (B + 255) / 256;
  hipLaunchKernelGGL(manifold_kernel, dim3(grid), dim3(256), 0, stream,
                     x, ws, out, B);
}